// Round 10
// baseline (290.216 us; speedup 1.0000x reference)
//
#include <hip/hip_runtime.h>

#define EPS_F   0.1f
#define INV_EPS 10.0f
#define NB 16
#define NN 512
#define ND 128
#define MAX_ITER 20
#define BPB 16                                        // blocks per batch
#define NEG_INF (-__builtin_inff())
// log(1/512 + 1e-8) computed in fp32 like the reference
#define LOG_MU (-6.2383195f)
#define LOG2E_F 1.4426950408889634f
#define KSC     (INV_EPS * LOG2E_F)                   // scale into log2 domain
#define INVK    (EPS_F * 0.6931471805599453f)         // 1/KSC
#define LM2     (LOG_MU * LOG2E_F)                    // LOG_MU in log2 domain

#define LD_REL(p)     __hip_atomic_load((p), __ATOMIC_RELAXED, __HIP_MEMORY_SCOPE_AGENT)
#define ST_REL(p, x)  __hip_atomic_store((p), (x), __ATOMIC_RELAXED, __HIP_MEMORY_SCOPE_AGENT)

// Persistent kernel, 256 blocks x 1024 thr (1/CU). bid = 16*t + b -> batch b's
// blocks on XCD b%8 (locality heuristic). C written once (GEMM; __threadfence
// publishes), immutable after; each block caches its 32-row stripe in REGISTERS
// pre-scaled by KSC (log2 domain): row frags cR2 + col frags cC2. All Sinkhorn
// math runs in log2 domain (exp2f/log2f = native v_exp/v_log), so inner loops
// are sub+sub+exp. One flag-sync per iteration: col-sweep threads publish their
// per-half (m,s) partials straight from registers (packed u64, relaxed agent
// atomics, double-buffered in ws) -> __syncthreads (vmcnt drain) -> tid0 sets
// flags[b][bt]=t+1 -> wave0 polls the batch's 16 flags -> combine: each thread
// loads 16 (stripe,half) partials for its column, LDS-merge halves -> v_new in
// LDS. u,v never touch global. Freeze: write-once slots frozenPub[b][t], leader
// decides at combine(t), applied at top of t+1 (uniform, deadlock-free; the lag
// is inert since err ~1e4 >> 1.6 can never cross 0.1*NB within 20 iters).

// ws float layout
#define WS_ERRPART  0       // 512 = 2(buf) x 16(b) x 16(bt)
#define WS_ERRB     512     // 320 = errB[t*16+b], init 1e30
#define WS_COSTPART 832     // 256
#define WS_FPUB     1088    // 320 ints: frozenPub[b*20+t], init 0
#define WS_FLAGS    1408    // 16 x 32 u32 (128B stride): flags[b*32+bt]
#define WS_BARCNT   1920    // 16 x 32 unsigned (128B stride)
#define WS_MSPART   2560    // u64[2][16][16][1024] = 4 MB (no init needed)
#define WS_TOTAL    2560    // zeroed region

__global__ void k_zero(float* __restrict__ ws) {
    int i = blockIdx.x * 256 + threadIdx.x;
    if (i >= WS_TOTAL) return;
    float val = 0.0f;
    if (i >= WS_ERRB && i < WS_ERRB + 320) val = 1e30f;
    ws[i] = val;                                      // zeros ints/unsigneds too
}

__global__ __launch_bounds__(1024, 4) void
k_sink(const float* __restrict__ x, const float* __restrict__ y,
       float* __restrict__ C, float* __restrict__ pi, float* __restrict__ cost,
       float* errPart, float* errB, float* costPart, int* frozenPub,
       unsigned* flags, unsigned* barCnt, unsigned long long* msPart) {
    __shared__ float As[32][132];                     // 528B rows: 16B-aligned b128
    __shared__ float Bs[32][132];
    __shared__ float xsqS[128];
    __shared__ float ysqS[128];
    __shared__ float vsS[512];                        // v (log2 dom), block-local
    __shared__ float usS[32];                         // u (log2 dom), own stripe
    __shared__ float mH[1024];
    __shared__ float sH[1024];
    __shared__ float partS[16];
    __shared__ int flagS;

    const int tid = threadIdx.x;
    const int bid = blockIdx.x;
    const int b  = bid & 15;
    const int bt = bid >> 4;                          // 0..15 within batch
    unsigned* cnt = barCnt + b * 32;
    unsigned* flagsB = flags + b * 32;
    unsigned bphase = 0;

    const int w = tid >> 6, l = tid & 63;             // 16 waves

    auto barrier_full = [&](bool flush) {
        ++bphase;
        __syncthreads();
        if (tid == 0) {
            if (flush) __threadfence();               // GEMM publish only
            __hip_atomic_fetch_add(cnt, 1u, __ATOMIC_RELAXED, __HIP_MEMORY_SCOPE_AGENT);
            while (LD_REL(cnt) < BPB * bphase)
                __builtin_amdgcn_s_sleep(1);
        }
        __syncthreads();
    };

    // ================= Phase 0: xsq/ysq + 128x128 GEMM tile =================
    {
        const int gi0 = (bt >> 2) * 128;
        const int gj0 = (bt & 3) * 128;
        for (int r = w; r < 128; r += 16) {
            const float* px = x + ((size_t)(b * NN + gi0 + r)) * ND;
            float a0 = px[l], a1 = px[l + 64];
            float ss = a0 * a0 + a1 * a1;
#pragma unroll
            for (int off = 32; off; off >>= 1) ss += __shfl_xor(ss, off, 64);
            if (l == 0) xsqS[r] = ss;
        }
        for (int r = w; r < 128; r += 16) {
            const float* py = y + ((size_t)(b * NN + gj0 + r)) * ND;
            float a0 = py[l], a1 = py[l + 64];
            float ss = a0 * a0 + a1 * a1;
#pragma unroll
            for (int off = 32; off; off >>= 1) ss += __shfl_xor(ss, off, 64);
            if (l == 0) ysqS[r] = ss;
        }
        const float* xb = x + ((size_t)b * NN + gi0) * ND;
        const float* yb = y + ((size_t)b * NN + gj0) * ND;
        int tx = tid & 31, ty = tid >> 5;             // 32 x 32 thread grid
        float acc[4][4] = {};
        for (int k0 = 0; k0 < ND; k0 += 32) {
            __syncthreads();
            {
                int r  = tid >> 3;                    // 0..127
                int kq = (tid & 7) << 2;              // 0..28
                float4 vx = *(const float4*)(xb + (size_t)r * ND + k0 + kq);
                float4 vy = *(const float4*)(yb + (size_t)r * ND + k0 + kq);
                As[kq + 0][r] = vx.x; As[kq + 1][r] = vx.y;
                As[kq + 2][r] = vx.z; As[kq + 3][r] = vx.w;
                Bs[kq + 0][r] = vy.x; Bs[kq + 1][r] = vy.y;
                Bs[kq + 2][r] = vy.z; Bs[kq + 3][r] = vy.w;
            }
            __syncthreads();
#pragma unroll
            for (int k = 0; k < 32; ++k) {
                float4 av = *(const float4*)&As[k][ty * 4];
                float4 bv = *(const float4*)&Bs[k][tx * 4];
                float ar[4] = {av.x, av.y, av.z, av.w};
                float br[4] = {bv.x, bv.y, bv.z, bv.w};
#pragma unroll
                for (int q = 0; q < 4; ++q)
#pragma unroll
                    for (int p = 0; p < 4; ++p) acc[q][p] += ar[q] * br[p];
            }
        }
#pragma unroll
        for (int q = 0; q < 4; ++q) {
            int il = ty * 4 + q;
            float xq = xsqS[il];
            float* Crow = C + ((size_t)(b * NN + gi0 + il)) * NN + gj0;
            float4 out;
            out.x = xq + ysqS[tx * 4 + 0] - 2.0f * acc[q][0];
            out.y = xq + ysqS[tx * 4 + 1] - 2.0f * acc[q][1];
            out.z = xq + ysqS[tx * 4 + 2] - 2.0f * acc[q][2];
            out.w = xq + ysqS[tx * 4 + 3] - 2.0f * acc[q][3];
            *(float4*)(Crow + tx * 4) = out;
        }
    }
    barrier_full(true);                               // publish C device-wide

    // ===== One-time C readback into registers, pre-scaled by KSC (log2 dom) =====
    float4 cR2[2][2];                                 // rows bt*32+2w+{0,1}
#pragma unroll
    for (int rr = 0; rr < 2; ++rr) {
        const float* Crow = C + ((size_t)(b * NN + bt * 32 + w * 2 + rr)) * NN;
        float4 a = *(const float4*)(Crow + 4 * l);
        float4 d = *(const float4*)(Crow + 256 + 4 * l);
        a.x *= KSC; a.y *= KSC; a.z *= KSC; a.w *= KSC;
        d.x *= KSC; d.y *= KSC; d.z *= KSC; d.w *= KSC;
        cR2[rr][0] = a; cR2[rr][1] = d;
    }
    float cC2[16];                                    // col j, rows h*16..+15
    {
        int j = tid & 511, h = tid >> 9;
        const float* Cc = C + ((size_t)(b * NN + bt * 32 + h * 16)) * NN + j;
#pragma unroll
        for (int r = 0; r < 16; ++r) cC2[r] = Cc[(size_t)r * NN] * KSC;
    }

    // ================= Sinkhorn iterations (1 flag-sync each) =================
    if (tid < 512) vsS[tid] = 0.0f;
    if (tid == 0)  flagS = 0;
    __syncthreads();
    float uPrev[2] = {0.0f, 0.0f};                    // log2-domain u, own rows
    int frozenLatch = 0;

    for (int t = 0; t < MAX_ITER; ++t) {
        if (flagS) break;                             // uniform (lagged decision)
        const int buf = t & 1;

        // ---- ROW sweep (log2 domain): u for own 2 rows/wave ----
        float4 v0 = *(const float4*)(vsS + 4 * l);
        float4 v1 = *(const float4*)(vsS + 256 + 4 * l);
        float duSum = 0.0f, unArr[2];
#pragma unroll
        for (int rr = 0; rr < 2; ++rr) {
            float4 c0 = cR2[rr][0], c1 = cR2[rr][1];
            float tv[8] = {v0.x - c0.x, v0.y - c0.y, v0.z - c0.z, v0.w - c0.w,
                           v1.x - c1.x, v1.y - c1.y, v1.z - c1.z, v1.w - c1.w};
            float m = tv[0];
#pragma unroll
            for (int k = 1; k < 8; ++k) m = fmaxf(m, tv[k]);
#pragma unroll
            for (int off = 32; off; off >>= 1)
                m = fmaxf(m, __shfl_xor(m, off, 64));
            float s = 0.0f;
#pragma unroll
            for (int k = 0; k < 8; ++k) s += exp2f(tv[k] - m);
#pragma unroll
            for (int off = 32; off; off >>= 1) s += __shfl_xor(s, off, 64);
            float un = LM2 - (m + log2f(s));          // u in log2 domain
            unArr[rr] = un;
            duSum += fabsf(un - uPrev[rr]);
            uPrev[rr] = un;
        }
        if (l == 0) {
            usS[w * 2 + 0] = unArr[0];
            usS[w * 2 + 1] = unArr[1];
            partS[w] = duSum;
        }
        __syncthreads();                              // A: usS + partS ready

        // ---- COL half-sweep from registers; publish (m,s) directly ----
        {
            int j = tid & 511, h = tid >> 9;
            float tvc[16];
#pragma unroll
            for (int r = 0; r < 16; ++r) tvc[r] = usS[h * 16 + r] - cC2[r];
            float m = tvc[0];
#pragma unroll
            for (int r = 1; r < 16; ++r) m = fmaxf(m, tvc[r]);
            float s = 0.0f;
#pragma unroll
            for (int r = 0; r < 16; ++r) s += exp2f(tvc[r] - m);
            unsigned long long up =
                ((unsigned long long)__float_as_uint(s) << 32) | __float_as_uint(m);
            ST_REL(msPart + (size_t)buf * 262144 + b * 16384 + bt * 1024 + tid, up);
        }
        if (tid == 0) {
            float e = 0.0f;
#pragma unroll
            for (int q = 0; q < 16; ++q) e += partS[q];
            ST_REL(errPart + buf * 256 + b * 16 + bt, e * INVK);  // e-domain err
        }
        __syncthreads();                              // B: all stores drained
        if (tid == 0) ST_REL(flagsB + bt, (unsigned)(t + 1));
        if (w == 0) {                                 // one polling wave per block
            const unsigned tgt = (unsigned)(t + 1);
            for (;;) {
                unsigned fv = (l < 16) ? LD_REL(flagsB + l) : tgt;
                if (__all(fv >= tgt)) break;
                __builtin_amdgcn_s_sleep(1);
            }
        }
        __syncthreads();                              // C: all partials visible

        if (tid == 0 && t >= 1)                       // slot t-1: write-once, ordered
            flagS = LD_REL(frozenPub + b * 20 + (t - 1));

        // ---- COMBINE: 16 (stripe,half) partials per thread for col j ----
        {
            int j = tid & 511, h = tid >> 9;          // h picks stripes h*8..h*8+7
            size_t base = (size_t)buf * 262144 + b * 16384 + j;
            unsigned long long up[16];
#pragma unroll
            for (int q = 0; q < 8; ++q) {
                up[2 * q]     = LD_REL(msPart + base + (size_t)(h * 8 + q) * 1024);
                up[2 * q + 1] = LD_REL(msPart + base + (size_t)(h * 8 + q) * 1024 + 512);
            }
            float mq[16], sq[16];
#pragma unroll
            for (int q = 0; q < 16; ++q) {
                mq[q] = __uint_as_float((unsigned)(up[q] & 0xffffffffu));
                sq[q] = __uint_as_float((unsigned)(up[q] >> 32));
            }
            float mm = mq[0];
#pragma unroll
            for (int q = 1; q < 16; ++q) mm = fmaxf(mm, mq[q]);
            float ss = 0.0f;
#pragma unroll
            for (int q = 0; q < 16; ++q) ss += sq[q] * exp2f(mq[q] - mm);
            mH[tid] = mm;
            sH[tid] = ss;
        }
        // leader: err bookkeeping + decision(t) -> slot t (off hot path)
        if (bt == 0 && w == 15) {
            float e = (l < 16) ? LD_REL(errPart + buf * 256 + b * 16 + l) : 0.0f;
#pragma unroll
            for (int off = 8; off; off >>= 1) e += __shfl_xor(e, off, 64);
            if (l == 0) ST_REL(errB + t * 16 + b, e);
            float g = (l < 16) ? ((l == b) ? e : LD_REL(errB + t * 16 + l)) : 0.0f;
#pragma unroll
            for (int off = 8; off; off >>= 1) g += __shfl_xor(g, off, 64);
            g = __shfl(g, 0, 64);
            frozenLatch |= (g < 0.1f * NB) ? 1 : 0;   // wave-uniform
            if (l == 0) ST_REL(frozenPub + b * 20 + t, frozenLatch);
        }
        __syncthreads();                              // D: mH/sH + flagS ready
        if (tid < 512) {
            float mm = mH[tid], ss = sH[tid];
            float m2 = mH[tid + 512], s2 = sH[tid + 512];
            float mn = fmaxf(mm, m2);
            ss = ss * exp2f(mm - mn) + s2 * exp2f(m2 - mn);
            vsS[tid] = LM2 - (mn + log2f(ss));        // v in log2 domain
        }
        __syncthreads();                              // E: vsS ready
    }

    // ===== PI phase (log2 dom): p = 2^(u2+v2-c2); cost = sum p*c2 / KSC =====
    float csum = 0.0f;
    {
        float4 v0 = *(const float4*)(vsS + 4 * l);
        float4 v1 = *(const float4*)(vsS + 256 + 4 * l);
#pragma unroll
        for (int rr = 0; rr < 2; ++rr) {
            int i = bt * 32 + w * 2 + rr;
            float uu = uPrev[rr];
            float* prow = pi + ((size_t)(b * NN + i)) * NN;
            float4 c0 = cR2[rr][0], c1 = cR2[rr][1];
            float4 p0, p1;
            p0.x = exp2f(uu + v0.x - c0.x);
            p0.y = exp2f(uu + v0.y - c0.y);
            p0.z = exp2f(uu + v0.z - c0.z);
            p0.w = exp2f(uu + v0.w - c0.w);
            p1.x = exp2f(uu + v1.x - c1.x);
            p1.y = exp2f(uu + v1.y - c1.y);
            p1.z = exp2f(uu + v1.z - c1.z);
            p1.w = exp2f(uu + v1.w - c1.w);
            *(float4*)(prow + 4 * l) = p0;
            *(float4*)(prow + 256 + 4 * l) = p1;
            csum += p0.x * c0.x + p0.y * c0.y + p0.z * c0.z + p0.w * c0.w +
                    p1.x * c1.x + p1.y * c1.y + p1.z * c1.z + p1.w * c1.w;
        }
    }
#pragma unroll
    for (int off = 32; off; off >>= 1) csum += __shfl_xor(csum, off, 64);
    if (l == 0) partS[w] = csum;
    __syncthreads();
    if (tid == 0) {
        float s = 0.0f;
#pragma unroll
        for (int q = 0; q < 16; ++q) s += partS[q];
        ST_REL(costPart + b * 16 + bt, s * INVK);     // back to raw-C domain
    }
    barrier_full(false);                              // cost partials visible
    if (bt == 0 && tid == 0) {
        float s = 0.0f;
        for (int q = 0; q < 16; ++q) s += LD_REL(costPart + b * 16 + q);
        cost[b] = s;                                  // plain store; kernel-end release
    }
}

extern "C" void kernel_launch(void* const* d_in, const int* in_sizes, int n_in,
                              void* d_out, int out_size, void* d_ws, size_t ws_size,
                              hipStream_t stream) {
    const float* x = (const float*)d_in[0];
    const float* y = (const float*)d_in[1];

    // Output layout: cost[16], pi[16*512*512], C[16*512*512]
    float* cost = (float*)d_out;
    float* pi   = cost + 16;
    float* C    = pi + (size_t)NB * NN * NN;

    float* f = (float*)d_ws;
    float* errPart  = f + WS_ERRPART;
    float* errB     = f + WS_ERRB;
    float* costPart = f + WS_COSTPART;
    int*   frozenPub = (int*)(f + WS_FPUB);
    unsigned* flags  = (unsigned*)(f + WS_FLAGS);
    unsigned* barCnt = (unsigned*)(f + WS_BARCNT);
    unsigned long long* msPart = (unsigned long long*)(f + WS_MSPART);

    hipLaunchKernelGGL(k_zero, dim3((WS_TOTAL + 255) / 256), dim3(256), 0, stream, f);

    void* args[] = {(void*)&x, (void*)&y, (void*)&C, (void*)&pi, (void*)&cost,
                    (void*)&errPart, (void*)&errB, (void*)&costPart,
                    (void*)&frozenPub, (void*)&flags, (void*)&barCnt, (void*)&msPart};
    hipError_t e = hipLaunchCooperativeKernel((const void*)k_sink, dim3(256), dim3(1024),
                                              args, 0, stream);
    if (e != hipSuccess) {
        // Fallback: plain launch. 256 blocks x 1024 thr, 1 block/CU -> co-resident.
        hipLaunchKernelGGL(k_sink, dim3(256), dim3(1024), 0, stream,
                           x, y, C, pi, cost, errPart, errB, costPart,
                           frozenPub, flags, barCnt, msPart);
    }
}

// Round 11
// 254.640 us; speedup vs baseline: 1.1397x; 1.1397x over previous
//
#include <hip/hip_runtime.h>

#define EPS_F   0.1f
#define INV_EPS 10.0f
#define NB 16
#define NN 512
#define ND 128
#define MAX_ITER 20
#define BPB 16                                        // blocks per batch
#define NEG_INF (-__builtin_inff())
// log(1/512 + 1e-8) computed in fp32 like the reference
#define LOG_MU (-6.2383195f)
#define LOG2E_F 1.4426950408889634f
#define KSC     (INV_EPS * LOG2E_F)                   // scale into log2 domain
#define INVK    (EPS_F * 0.6931471805599453f)         // 1/KSC
#define LM2     (LOG_MU * LOG2E_F)                    // LOG_MU in log2 domain

#define LD_REL(p)     __hip_atomic_load((p), __ATOMIC_RELAXED, __HIP_MEMORY_SCOPE_AGENT)
#define ST_REL(p, x)  __hip_atomic_store((p), (x), __ATOMIC_RELAXED, __HIP_MEMORY_SCOPE_AGENT)

// Persistent kernel, 256 blocks x 1024 thr (1/CU). bid = 16*t + b -> batch b's
// blocks on XCD b%8 (locality heuristic). C written once (GEMM; __threadfence
// publishes), immutable after; each block caches its 32-row stripe in REGISTERS
// pre-scaled by KSC (log2 domain). All Sinkhorn math in log2 domain (exp2f /
// log2f = native v_exp/v_log): inner loops are sub+max / sub+exp2.
// r9-proven sync fabric (r10's publish-halves variant regressed — doubled
// coherence-point traffic): col sweep halves -> LDS pre-combine -> publish 512
// u64/block (packed (m,s), relaxed agent atomics, double-buffered in ws) ->
// __syncthreads (vmcnt drain) -> tid0 sets flags[b][bt]=t+1 -> wave0 polls the
// batch's 16 flags (one line) -> combine: 8 stripe-loads/thread, LDS half-merge
// -> v_new in LDS. u,v never touch global. Freeze: write-once frozenPub[b][t];
// leader decides at combine(t), applied at top of t+1 (uniform, deadlock-free;
// the 1-iter lag is inert: err ~1e4 >> 1.6 cannot cross 0.1*NB in 20 iters).

__device__ __forceinline__ void lse_comb2(float& m, float& s, float m2, float s2) {
    float mn = fmaxf(m, m2);
    s = s * exp2f(m - mn) + s2 * exp2f(m2 - mn);
    m = mn;
}

// ws float layout
#define WS_ERRPART  0       // 512 = 2(buf) x 16(b) x 16(bt)
#define WS_ERRB     512     // 320 = errB[t*16+b], init 1e30
#define WS_COSTPART 832     // 256
#define WS_FPUB     1088    // 320 ints: frozenPub[b*20+t], init 0
#define WS_FLAGS    1408    // 16 x 32 u32 (128B stride): flags[b*32+bt]
#define WS_BARCNT   1920    // 16 x 32 unsigned (128B stride)
#define WS_MSPART   2560    // u64[2][16][16][512] = 2 MB (no init needed)
#define WS_TOTAL    2560    // zeroed region

__global__ void k_zero(float* __restrict__ ws) {
    int i = blockIdx.x * 256 + threadIdx.x;
    if (i >= WS_TOTAL) return;
    float val = 0.0f;
    if (i >= WS_ERRB && i < WS_ERRB + 320) val = 1e30f;
    ws[i] = val;                                      // zeros ints/unsigneds too
}

__global__ __launch_bounds__(1024, 4) void
k_sink(const float* __restrict__ x, const float* __restrict__ y,
       float* __restrict__ C, float* __restrict__ pi, float* __restrict__ cost,
       float* errPart, float* errB, float* costPart, int* frozenPub,
       unsigned* flags, unsigned* barCnt, unsigned long long* msPart) {
    __shared__ float As[32][132];                     // 528B rows: 16B-aligned b128
    __shared__ float Bs[32][132];
    __shared__ float xsqS[128];
    __shared__ float ysqS[128];
    __shared__ float vsS[512];                        // v (log2 dom), block-local
    __shared__ float usS[32];                         // u (log2 dom), own stripe
    __shared__ float mH[1024];
    __shared__ float sH[1024];
    __shared__ float partS[16];
    __shared__ int flagS;

    const int tid = threadIdx.x;
    const int bid = blockIdx.x;
    const int b  = bid & 15;
    const int bt = bid >> 4;                          // 0..15 within batch
    unsigned* cnt = barCnt + b * 32;
    unsigned* flagsB = flags + b * 32;
    unsigned bphase = 0;

    const int w = tid >> 6, l = tid & 63;             // 16 waves

    auto barrier_full = [&](bool flush) {
        ++bphase;
        __syncthreads();
        if (tid == 0) {
            if (flush) __threadfence();               // GEMM publish only
            __hip_atomic_fetch_add(cnt, 1u, __ATOMIC_RELAXED, __HIP_MEMORY_SCOPE_AGENT);
            while (LD_REL(cnt) < BPB * bphase)
                __builtin_amdgcn_s_sleep(1);
        }
        __syncthreads();
    };

    // ================= Phase 0: xsq/ysq + 128x128 GEMM tile =================
    {
        const int gi0 = (bt >> 2) * 128;
        const int gj0 = (bt & 3) * 128;
        for (int r = w; r < 128; r += 16) {
            const float* px = x + ((size_t)(b * NN + gi0 + r)) * ND;
            float a0 = px[l], a1 = px[l + 64];
            float ss = a0 * a0 + a1 * a1;
#pragma unroll
            for (int off = 32; off; off >>= 1) ss += __shfl_xor(ss, off, 64);
            if (l == 0) xsqS[r] = ss;
        }
        for (int r = w; r < 128; r += 16) {
            const float* py = y + ((size_t)(b * NN + gj0 + r)) * ND;
            float a0 = py[l], a1 = py[l + 64];
            float ss = a0 * a0 + a1 * a1;
#pragma unroll
            for (int off = 32; off; off >>= 1) ss += __shfl_xor(ss, off, 64);
            if (l == 0) ysqS[r] = ss;
        }
        const float* xb = x + ((size_t)b * NN + gi0) * ND;
        const float* yb = y + ((size_t)b * NN + gj0) * ND;
        int tx = tid & 31, ty = tid >> 5;             // 32 x 32 thread grid
        float acc[4][4] = {};
        for (int k0 = 0; k0 < ND; k0 += 32) {
            __syncthreads();
            {
                int r  = tid >> 3;                    // 0..127
                int kq = (tid & 7) << 2;              // 0..28
                float4 vx = *(const float4*)(xb + (size_t)r * ND + k0 + kq);
                float4 vy = *(const float4*)(yb + (size_t)r * ND + k0 + kq);
                As[kq + 0][r] = vx.x; As[kq + 1][r] = vx.y;
                As[kq + 2][r] = vx.z; As[kq + 3][r] = vx.w;
                Bs[kq + 0][r] = vy.x; Bs[kq + 1][r] = vy.y;
                Bs[kq + 2][r] = vy.z; Bs[kq + 3][r] = vy.w;
            }
            __syncthreads();
#pragma unroll
            for (int k = 0; k < 32; ++k) {
                float4 av = *(const float4*)&As[k][ty * 4];
                float4 bv = *(const float4*)&Bs[k][tx * 4];
                float ar[4] = {av.x, av.y, av.z, av.w};
                float br[4] = {bv.x, bv.y, bv.z, bv.w};
#pragma unroll
                for (int q = 0; q < 4; ++q)
#pragma unroll
                    for (int p = 0; p < 4; ++p) acc[q][p] += ar[q] * br[p];
            }
        }
#pragma unroll
        for (int q = 0; q < 4; ++q) {
            int il = ty * 4 + q;
            float xq = xsqS[il];
            float* Crow = C + ((size_t)(b * NN + gi0 + il)) * NN + gj0;
            float4 out;
            out.x = xq + ysqS[tx * 4 + 0] - 2.0f * acc[q][0];
            out.y = xq + ysqS[tx * 4 + 1] - 2.0f * acc[q][1];
            out.z = xq + ysqS[tx * 4 + 2] - 2.0f * acc[q][2];
            out.w = xq + ysqS[tx * 4 + 3] - 2.0f * acc[q][3];
            *(float4*)(Crow + tx * 4) = out;
        }
    }
    barrier_full(true);                               // publish C device-wide

    // ===== One-time C readback into registers, pre-scaled by KSC (log2 dom) =====
    float4 cR2[2][2];                                 // rows bt*32+2w+{0,1}
#pragma unroll
    for (int rr = 0; rr < 2; ++rr) {
        const float* Crow = C + ((size_t)(b * NN + bt * 32 + w * 2 + rr)) * NN;
        float4 a = *(const float4*)(Crow + 4 * l);
        float4 d = *(const float4*)(Crow + 256 + 4 * l);
        a.x *= KSC; a.y *= KSC; a.z *= KSC; a.w *= KSC;
        d.x *= KSC; d.y *= KSC; d.z *= KSC; d.w *= KSC;
        cR2[rr][0] = a; cR2[rr][1] = d;
    }
    float cC2[16];                                    // col j, rows h*16..+15
    {
        int j = tid & 511, h = tid >> 9;
        const float* Cc = C + ((size_t)(b * NN + bt * 32 + h * 16)) * NN + j;
#pragma unroll
        for (int r = 0; r < 16; ++r) cC2[r] = Cc[(size_t)r * NN] * KSC;
    }

    // ================= Sinkhorn iterations (1 flag-sync each) =================
    if (tid < 512) vsS[tid] = 0.0f;
    if (tid == 0)  flagS = 0;
    __syncthreads();
    float uPrev[2] = {0.0f, 0.0f};                    // log2-domain u, own rows
    int frozenLatch = 0;

    for (int t = 0; t < MAX_ITER; ++t) {
        if (flagS) break;                             // uniform (lagged decision)
        const int buf = t & 1;

        // ---- ROW sweep (log2 domain): u for own 2 rows/wave ----
        float4 v0 = *(const float4*)(vsS + 4 * l);
        float4 v1 = *(const float4*)(vsS + 256 + 4 * l);
        float duSum = 0.0f, unArr[2];
#pragma unroll
        for (int rr = 0; rr < 2; ++rr) {
            float4 c0 = cR2[rr][0], c1 = cR2[rr][1];
            float tv[8] = {v0.x - c0.x, v0.y - c0.y, v0.z - c0.z, v0.w - c0.w,
                           v1.x - c1.x, v1.y - c1.y, v1.z - c1.z, v1.w - c1.w};
            float m = tv[0];
#pragma unroll
            for (int k = 1; k < 8; ++k) m = fmaxf(m, tv[k]);
#pragma unroll
            for (int off = 32; off; off >>= 1)        // max first: no exps in shfl
                m = fmaxf(m, __shfl_xor(m, off, 64));
            float s = 0.0f;
#pragma unroll
            for (int k = 0; k < 8; ++k) s += exp2f(tv[k] - m);
#pragma unroll
            for (int off = 32; off; off >>= 1) s += __shfl_xor(s, off, 64);
            float un = LM2 - (m + log2f(s));          // u in log2 domain
            unArr[rr] = un;
            duSum += fabsf(un - uPrev[rr]);
            uPrev[rr] = un;
        }
        if (l == 0) {
            usS[w * 2 + 0] = unArr[0];
            usS[w * 2 + 1] = unArr[1];
            partS[w] = duSum;
        }
        __syncthreads();                              // A: usS + partS ready

        // ---- COL half-sweep from registers (16 rows per thread) ----
        {
            int h = tid >> 9;
            float tvc[16];
#pragma unroll
            for (int r = 0; r < 16; ++r) tvc[r] = usS[h * 16 + r] - cC2[r];
            float m = tvc[0];
#pragma unroll
            for (int r = 1; r < 16; ++r) m = fmaxf(m, tvc[r]);
            float s = 0.0f;
#pragma unroll
            for (int r = 0; r < 16; ++r) s += exp2f(tvc[r] - m);
            mH[tid] = m;
            sH[tid] = s;
        }
        __syncthreads();
        if (tid < 512) {                              // pre-combine halves, publish
            float mm = mH[tid], ss = sH[tid];
            lse_comb2(mm, ss, mH[tid + 512], sH[tid + 512]);
            unsigned long long up =
                ((unsigned long long)__float_as_uint(ss) << 32) | __float_as_uint(mm);
            ST_REL(msPart + (size_t)buf * 131072 + b * 8192 + bt * 512 + tid, up);
        }
        if (tid == 0) {
            float e = 0.0f;
#pragma unroll
            for (int q = 0; q < 16; ++q) e += partS[q];
            ST_REL(errPart + buf * 256 + b * 16 + bt, e * INVK);  // e-domain err
        }
        __syncthreads();                              // B: all stores drained
        if (tid == 0) ST_REL(flagsB + bt, (unsigned)(t + 1));
        if (w == 0) {                                 // one polling wave per block
            const unsigned tgt = (unsigned)(t + 1);
            for (;;) {
                unsigned fv = (l < 16) ? LD_REL(flagsB + l) : tgt;
                if (__all(fv >= tgt)) break;
                __builtin_amdgcn_s_sleep(1);
            }
        }
        __syncthreads();                              // C: all partials visible

        if (tid == 0 && t >= 1)                       // slot t-1: write-once, ordered
            flagS = LD_REL(frozenPub + b * 20 + (t - 1));

        // ---- COMBINE: 8 stripe-partials per thread for col j, half h ----
        {
            int j = tid & 511, h = tid >> 9;
            size_t base = (size_t)buf * 131072 + b * 8192 + j;
            unsigned long long up[8];
#pragma unroll
            for (int q = 0; q < 8; ++q)
                up[q] = LD_REL(msPart + base + (size_t)(h * 8 + q) * 512);
            float mq[8], sq[8];
#pragma unroll
            for (int q = 0; q < 8; ++q) {
                mq[q] = __uint_as_float((unsigned)(up[q] & 0xffffffffu));
                sq[q] = __uint_as_float((unsigned)(up[q] >> 32));
            }
            float mm = mq[0];
#pragma unroll
            for (int q = 1; q < 8; ++q) mm = fmaxf(mm, mq[q]);
            float ss = 0.0f;
#pragma unroll
            for (int q = 0; q < 8; ++q) ss += sq[q] * exp2f(mq[q] - mm);
            mH[tid] = mm;
            sH[tid] = ss;
        }
        // leader: err bookkeeping + decision(t) -> slot t (off hot path)
        if (bt == 0 && w == 15) {
            float e = (l < 16) ? LD_REL(errPart + buf * 256 + b * 16 + l) : 0.0f;
#pragma unroll
            for (int off = 8; off; off >>= 1) e += __shfl_xor(e, off, 64);
            if (l == 0) ST_REL(errB + t * 16 + b, e);
            float g = (l < 16) ? ((l == b) ? e : LD_REL(errB + t * 16 + l)) : 0.0f;
#pragma unroll
            for (int off = 8; off; off >>= 1) g += __shfl_xor(g, off, 64);
            g = __shfl(g, 0, 64);
            frozenLatch |= (g < 0.1f * NB) ? 1 : 0;   // wave-uniform
            if (l == 0) ST_REL(frozenPub + b * 20 + t, frozenLatch);
        }
        __syncthreads();                              // D: mH/sH + flagS ready
        if (tid < 512) {
            float mm = mH[tid], ss = sH[tid];
            float m2 = mH[tid + 512], s2 = sH[tid + 512];
            float mn = fmaxf(mm, m2);
            ss = ss * exp2f(mm - mn) + s2 * exp2f(m2 - mn);
            vsS[tid] = LM2 - (mn + log2f(ss));        // v in log2 domain
        }
        __syncthreads();                              // E: vsS ready
    }

    // ===== PI phase (log2 dom): p = 2^(u2+v2-c2); cost = sum p*c2 / KSC =====
    float csum = 0.0f;
    {
        float4 v0 = *(const float4*)(vsS + 4 * l);
        float4 v1 = *(const float4*)(vsS + 256 + 4 * l);
#pragma unroll
        for (int rr = 0; rr < 2; ++rr) {
            int i = bt * 32 + w * 2 + rr;
            float uu = uPrev[rr];
            float* prow = pi + ((size_t)(b * NN + i)) * NN;
            float4 c0 = cR2[rr][0], c1 = cR2[rr][1];
            float4 p0, p1;
            p0.x = exp2f(uu + v0.x - c0.x);
            p0.y = exp2f(uu + v0.y - c0.y);
            p0.z = exp2f(uu + v0.z - c0.z);
            p0.w = exp2f(uu + v0.w - c0.w);
            p1.x = exp2f(uu + v1.x - c1.x);
            p1.y = exp2f(uu + v1.y - c1.y);
            p1.z = exp2f(uu + v1.z - c1.z);
            p1.w = exp2f(uu + v1.w - c1.w);
            *(float4*)(prow + 4 * l) = p0;
            *(float4*)(prow + 256 + 4 * l) = p1;
            csum += p0.x * c0.x + p0.y * c0.y + p0.z * c0.z + p0.w * c0.w +
                    p1.x * c1.x + p1.y * c1.y + p1.z * c1.z + p1.w * c1.w;
        }
    }
#pragma unroll
    for (int off = 32; off; off >>= 1) csum += __shfl_xor(csum, off, 64);
    if (l == 0) partS[w] = csum;
    __syncthreads();
    if (tid == 0) {
        float s = 0.0f;
#pragma unroll
        for (int q = 0; q < 16; ++q) s += partS[q];
        ST_REL(costPart + b * 16 + bt, s * INVK);     // back to raw-C domain
    }
    barrier_full(false);                              // cost partials visible
    if (bt == 0 && tid == 0) {
        float s = 0.0f;
        for (int q = 0; q < 16; ++q) s += LD_REL(costPart + b * 16 + q);
        cost[b] = s;                                  // plain store; kernel-end release
    }
}

extern "C" void kernel_launch(void* const* d_in, const int* in_sizes, int n_in,
                              void* d_out, int out_size, void* d_ws, size_t ws_size,
                              hipStream_t stream) {
    const float* x = (const float*)d_in[0];
    const float* y = (const float*)d_in[1];

    // Output layout: cost[16], pi[16*512*512], C[16*512*512]
    float* cost = (float*)d_out;
    float* pi   = cost + 16;
    float* C    = pi + (size_t)NB * NN * NN;

    float* f = (float*)d_ws;
    float* errPart  = f + WS_ERRPART;
    float* errB     = f + WS_ERRB;
    float* costPart = f + WS_COSTPART;
    int*   frozenPub = (int*)(f + WS_FPUB);
    unsigned* flags  = (unsigned*)(f + WS_FLAGS);
    unsigned* barCnt = (unsigned*)(f + WS_BARCNT);
    unsigned long long* msPart = (unsigned long long*)(f + WS_MSPART);

    hipLaunchKernelGGL(k_zero, dim3((WS_TOTAL + 255) / 256), dim3(256), 0, stream, f);

    void* args[] = {(void*)&x, (void*)&y, (void*)&C, (void*)&pi, (void*)&cost,
                    (void*)&errPart, (void*)&errB, (void*)&costPart,
                    (void*)&frozenPub, (void*)&flags, (void*)&barCnt, (void*)&msPart};
    hipError_t e = hipLaunchCooperativeKernel((const void*)k_sink, dim3(256), dim3(1024),
                                              args, 0, stream);
    if (e != hipSuccess) {
        // Fallback: plain launch. 256 blocks x 1024 thr, 1 block/CU -> co-resident.
        hipLaunchKernelGGL(k_sink, dim3(256), dim3(1024), 0, stream,
                           x, y, C, pi, cost, errPart, errB, costPart,
                           frozenPub, flags, barCnt, msPart);
    }
}

// Round 12
// 236.824 us; speedup vs baseline: 1.2254x; 1.0752x over previous
//
#include <hip/hip_runtime.h>

#define EPS_F   0.1f
#define INV_EPS 10.0f
#define NB 16
#define NN 512
#define ND 128
#define MAX_ITER 20
#define BPB 16                                        // blocks per batch
#define NEG_INF (-__builtin_inff())
// log(1/512 + 1e-8) computed in fp32 like the reference
#define LOG_MU (-6.2383195f)
#define LOG2E_F 1.4426950408889634f
#define KSC     (INV_EPS * LOG2E_F)                   // scale into log2 domain
#define INVK    (EPS_F * 0.6931471805599453f)         // 1/KSC
#define LM2     (LOG_MU * LOG2E_F)                    // LOG_MU in log2 domain

// Native transcendentals: raw v_exp_f32 / v_log_f32 (the precise OCML exp2f/
// log2f wrappers cost several VALU ops per call — r11's +17us VALU regression).
#define EXP2(x) __builtin_amdgcn_exp2f(x)
#define LOG2(x) __builtin_amdgcn_logf(x)

#define LD_REL(p)     __hip_atomic_load((p), __ATOMIC_RELAXED, __HIP_MEMORY_SCOPE_AGENT)
#define ST_REL(p, x)  __hip_atomic_store((p), (x), __ATOMIC_RELAXED, __HIP_MEMORY_SCOPE_AGENT)

// Persistent kernel, 256 blocks x 1024 thr (1/CU). bid = 16*t + b -> batch b's
// blocks on XCD b%8 (locality heuristic). C written once (GEMM; __threadfence
// publishes), immutable after; each block caches its 32-row stripe in REGISTERS
// pre-scaled by KSC (log2 domain). All Sinkhorn math in log2 domain: inner
// loops are v_sub + v_max / v_sub + v_exp. r9-proven sync fabric: col sweep
// halves -> LDS pre-combine -> publish 512 u64/block (packed (m,s), relaxed
// agent atomics, double-buffered in ws) -> __syncthreads (vmcnt drain) -> tid0
// sets flags[b][bt]=t+1 -> wave0 polls the batch's 16 flags (one line) ->
// combine: 8 stripe-loads/thread, LDS half-merge -> v_new in LDS. u,v never
// touch global. Freeze: write-once frozenPub[b][t]; leader decides at
// combine(t), applied at top of t+1 (uniform, deadlock-free; the 1-iter lag is
// inert: err ~1e4 >> 1.6 cannot cross 0.1*NB in 20 iters).

__device__ __forceinline__ void lse_comb2(float& m, float& s, float m2, float s2) {
    float mn = fmaxf(m, m2);
    s = s * EXP2(m - mn) + s2 * EXP2(m2 - mn);
    m = mn;
}

// ws float layout
#define WS_ERRPART  0       // 512 = 2(buf) x 16(b) x 16(bt)
#define WS_ERRB     512     // 320 = errB[t*16+b], init 1e30
#define WS_COSTPART 832     // 256
#define WS_FPUB     1088    // 320 ints: frozenPub[b*20+t], init 0
#define WS_FLAGS    1408    // 16 x 32 u32 (128B stride): flags[b*32+bt]
#define WS_BARCNT   1920    // 16 x 32 unsigned (128B stride)
#define WS_MSPART   2560    // u64[2][16][16][512] = 2 MB (no init needed)
#define WS_TOTAL    2560    // zeroed region

__global__ void k_zero(float* __restrict__ ws) {
    int i = blockIdx.x * 256 + threadIdx.x;
    if (i >= WS_TOTAL) return;
    float val = 0.0f;
    if (i >= WS_ERRB && i < WS_ERRB + 320) val = 1e30f;
    ws[i] = val;                                      // zeros ints/unsigneds too
}

__global__ __launch_bounds__(1024, 4) void
k_sink(const float* __restrict__ x, const float* __restrict__ y,
       float* __restrict__ C, float* __restrict__ pi, float* __restrict__ cost,
       float* errPart, float* errB, float* costPart, int* frozenPub,
       unsigned* flags, unsigned* barCnt, unsigned long long* msPart) {
    __shared__ float As[32][132];                     // 528B rows: 16B-aligned b128
    __shared__ float Bs[32][132];
    __shared__ float xsqS[128];
    __shared__ float ysqS[128];
    __shared__ float vsS[512];                        // v (log2 dom), block-local
    __shared__ float usS[32];                         // u (log2 dom), own stripe
    __shared__ float mH[1024];
    __shared__ float sH[1024];
    __shared__ float partS[16];
    __shared__ int flagS;

    const int tid = threadIdx.x;
    const int bid = blockIdx.x;
    const int b  = bid & 15;
    const int bt = bid >> 4;                          // 0..15 within batch
    unsigned* cnt = barCnt + b * 32;
    unsigned* flagsB = flags + b * 32;
    unsigned bphase = 0;

    const int w = tid >> 6, l = tid & 63;             // 16 waves

    auto barrier_full = [&](bool flush) {
        ++bphase;
        __syncthreads();
        if (tid == 0) {
            if (flush) __threadfence();               // GEMM publish only
            __hip_atomic_fetch_add(cnt, 1u, __ATOMIC_RELAXED, __HIP_MEMORY_SCOPE_AGENT);
            while (LD_REL(cnt) < BPB * bphase)
                __builtin_amdgcn_s_sleep(1);
        }
        __syncthreads();
    };

    // ================= Phase 0: xsq/ysq + 128x128 GEMM tile =================
    {
        const int gi0 = (bt >> 2) * 128;
        const int gj0 = (bt & 3) * 128;
        for (int r = w; r < 128; r += 16) {
            const float* px = x + ((size_t)(b * NN + gi0 + r)) * ND;
            float a0 = px[l], a1 = px[l + 64];
            float ss = a0 * a0 + a1 * a1;
#pragma unroll
            for (int off = 32; off; off >>= 1) ss += __shfl_xor(ss, off, 64);
            if (l == 0) xsqS[r] = ss;
        }
        for (int r = w; r < 128; r += 16) {
            const float* py = y + ((size_t)(b * NN + gj0 + r)) * ND;
            float a0 = py[l], a1 = py[l + 64];
            float ss = a0 * a0 + a1 * a1;
#pragma unroll
            for (int off = 32; off; off >>= 1) ss += __shfl_xor(ss, off, 64);
            if (l == 0) ysqS[r] = ss;
        }
        const float* xb = x + ((size_t)b * NN + gi0) * ND;
        const float* yb = y + ((size_t)b * NN + gj0) * ND;
        int tx = tid & 31, ty = tid >> 5;             // 32 x 32 thread grid
        float acc[4][4] = {};
        for (int k0 = 0; k0 < ND; k0 += 32) {
            __syncthreads();
            {
                int r  = tid >> 3;                    // 0..127
                int kq = (tid & 7) << 2;              // 0..28
                float4 vx = *(const float4*)(xb + (size_t)r * ND + k0 + kq);
                float4 vy = *(const float4*)(yb + (size_t)r * ND + k0 + kq);
                As[kq + 0][r] = vx.x; As[kq + 1][r] = vx.y;
                As[kq + 2][r] = vx.z; As[kq + 3][r] = vx.w;
                Bs[kq + 0][r] = vy.x; Bs[kq + 1][r] = vy.y;
                Bs[kq + 2][r] = vy.z; Bs[kq + 3][r] = vy.w;
            }
            __syncthreads();
#pragma unroll
            for (int k = 0; k < 32; ++k) {
                float4 av = *(const float4*)&As[k][ty * 4];
                float4 bv = *(const float4*)&Bs[k][tx * 4];
                float ar[4] = {av.x, av.y, av.z, av.w};
                float br[4] = {bv.x, bv.y, bv.z, bv.w};
#pragma unroll
                for (int q = 0; q < 4; ++q)
#pragma unroll
                    for (int p = 0; p < 4; ++p) acc[q][p] += ar[q] * br[p];
            }
        }
#pragma unroll
        for (int q = 0; q < 4; ++q) {
            int il = ty * 4 + q;
            float xq = xsqS[il];
            float* Crow = C + ((size_t)(b * NN + gi0 + il)) * NN + gj0;
            float4 out;
            out.x = xq + ysqS[tx * 4 + 0] - 2.0f * acc[q][0];
            out.y = xq + ysqS[tx * 4 + 1] - 2.0f * acc[q][1];
            out.z = xq + ysqS[tx * 4 + 2] - 2.0f * acc[q][2];
            out.w = xq + ysqS[tx * 4 + 3] - 2.0f * acc[q][3];
            *(float4*)(Crow + tx * 4) = out;
        }
    }
    barrier_full(true);                               // publish C device-wide

    // ===== One-time C readback into registers, pre-scaled by KSC (log2 dom) =====
    float4 cR2[2][2];                                 // rows bt*32+2w+{0,1}
#pragma unroll
    for (int rr = 0; rr < 2; ++rr) {
        const float* Crow = C + ((size_t)(b * NN + bt * 32 + w * 2 + rr)) * NN;
        float4 a = *(const float4*)(Crow + 4 * l);
        float4 d = *(const float4*)(Crow + 256 + 4 * l);
        a.x *= KSC; a.y *= KSC; a.z *= KSC; a.w *= KSC;
        d.x *= KSC; d.y *= KSC; d.z *= KSC; d.w *= KSC;
        cR2[rr][0] = a; cR2[rr][1] = d;
    }
    float cC2[16];                                    // col j, rows h*16..+15
    {
        int j = tid & 511, h = tid >> 9;
        const float* Cc = C + ((size_t)(b * NN + bt * 32 + h * 16)) * NN + j;
#pragma unroll
        for (int r = 0; r < 16; ++r) cC2[r] = Cc[(size_t)r * NN] * KSC;
    }

    // ================= Sinkhorn iterations (1 flag-sync each) =================
    if (tid < 512) vsS[tid] = 0.0f;
    if (tid == 0)  flagS = 0;
    __syncthreads();
    float uPrev[2] = {0.0f, 0.0f};                    // log2-domain u, own rows
    int frozenLatch = 0;

    for (int t = 0; t < MAX_ITER; ++t) {
        if (flagS) break;                             // uniform (lagged decision)
        const int buf = t & 1;

        // ---- ROW sweep (log2 domain): u for own 2 rows/wave ----
        float4 v0 = *(const float4*)(vsS + 4 * l);
        float4 v1 = *(const float4*)(vsS + 256 + 4 * l);
        float duSum = 0.0f, unArr[2];
#pragma unroll
        for (int rr = 0; rr < 2; ++rr) {
            float4 c0 = cR2[rr][0], c1 = cR2[rr][1];
            float tv[8] = {v0.x - c0.x, v0.y - c0.y, v0.z - c0.z, v0.w - c0.w,
                           v1.x - c1.x, v1.y - c1.y, v1.z - c1.z, v1.w - c1.w};
            float m = tv[0];
#pragma unroll
            for (int k = 1; k < 8; ++k) m = fmaxf(m, tv[k]);
#pragma unroll
            for (int off = 32; off; off >>= 1)        // max first: no exps in shfl
                m = fmaxf(m, __shfl_xor(m, off, 64));
            float s = 0.0f;
#pragma unroll
            for (int k = 0; k < 8; ++k) s += EXP2(tv[k] - m);
#pragma unroll
            for (int off = 32; off; off >>= 1) s += __shfl_xor(s, off, 64);
            float un = LM2 - (m + LOG2(s));           // u in log2 domain
            unArr[rr] = un;
            duSum += fabsf(un - uPrev[rr]);
            uPrev[rr] = un;
        }
        if (l == 0) {
            usS[w * 2 + 0] = unArr[0];
            usS[w * 2 + 1] = unArr[1];
            partS[w] = duSum;
        }
        __syncthreads();                              // A: usS + partS ready

        // ---- COL half-sweep from registers (16 rows per thread) ----
        {
            int h = tid >> 9;
            float tvc[16];
#pragma unroll
            for (int r = 0; r < 16; ++r) tvc[r] = usS[h * 16 + r] - cC2[r];
            float m = tvc[0];
#pragma unroll
            for (int r = 1; r < 16; ++r) m = fmaxf(m, tvc[r]);
            float s = 0.0f;
#pragma unroll
            for (int r = 0; r < 16; ++r) s += EXP2(tvc[r] - m);
            mH[tid] = m;
            sH[tid] = s;
        }
        __syncthreads();
        if (tid < 512) {                              // pre-combine halves, publish
            float mm = mH[tid], ss = sH[tid];
            lse_comb2(mm, ss, mH[tid + 512], sH[tid + 512]);
            unsigned long long up =
                ((unsigned long long)__float_as_uint(ss) << 32) | __float_as_uint(mm);
            ST_REL(msPart + (size_t)buf * 131072 + b * 8192 + bt * 512 + tid, up);
        }
        if (tid == 0) {
            float e = 0.0f;
#pragma unroll
            for (int q = 0; q < 16; ++q) e += partS[q];
            ST_REL(errPart + buf * 256 + b * 16 + bt, e * INVK);  // e-domain err
        }
        __syncthreads();                              // B: all stores drained
        if (tid == 0) ST_REL(flagsB + bt, (unsigned)(t + 1));
        if (w == 0) {                                 // one polling wave per block
            const unsigned tgt = (unsigned)(t + 1);
            for (;;) {
                unsigned fv = (l < 16) ? LD_REL(flagsB + l) : tgt;
                if (__all(fv >= tgt)) break;
                __builtin_amdgcn_s_sleep(1);
            }
        }
        __syncthreads();                              // C: all partials visible

        if (tid == 0 && t >= 1)                       // slot t-1: write-once, ordered
            flagS = LD_REL(frozenPub + b * 20 + (t - 1));

        // ---- COMBINE: 8 stripe-partials per thread for col j, half h ----
        {
            int j = tid & 511, h = tid >> 9;
            size_t base = (size_t)buf * 131072 + b * 8192 + j;
            unsigned long long up[8];
#pragma unroll
            for (int q = 0; q < 8; ++q)
                up[q] = LD_REL(msPart + base + (size_t)(h * 8 + q) * 512);
            float mq[8], sq[8];
#pragma unroll
            for (int q = 0; q < 8; ++q) {
                mq[q] = __uint_as_float((unsigned)(up[q] & 0xffffffffu));
                sq[q] = __uint_as_float((unsigned)(up[q] >> 32));
            }
            float mm = mq[0];
#pragma unroll
            for (int q = 1; q < 8; ++q) mm = fmaxf(mm, mq[q]);
            float ss = 0.0f;
#pragma unroll
            for (int q = 0; q < 8; ++q) ss += sq[q] * EXP2(mq[q] - mm);
            mH[tid] = mm;
            sH[tid] = ss;
        }
        // leader: err bookkeeping + decision(t) -> slot t (off hot path)
        if (bt == 0 && w == 15) {
            float e = (l < 16) ? LD_REL(errPart + buf * 256 + b * 16 + l) : 0.0f;
#pragma unroll
            for (int off = 8; off; off >>= 1) e += __shfl_xor(e, off, 64);
            if (l == 0) ST_REL(errB + t * 16 + b, e);
            float g = (l < 16) ? ((l == b) ? e : LD_REL(errB + t * 16 + l)) : 0.0f;
#pragma unroll
            for (int off = 8; off; off >>= 1) g += __shfl_xor(g, off, 64);
            g = __shfl(g, 0, 64);
            frozenLatch |= (g < 0.1f * NB) ? 1 : 0;   // wave-uniform
            if (l == 0) ST_REL(frozenPub + b * 20 + t, frozenLatch);
        }
        __syncthreads();                              // D: mH/sH + flagS ready
        if (tid < 512) {
            float mm = mH[tid], ss = sH[tid];
            float m2 = mH[tid + 512], s2 = sH[tid + 512];
            float mn = fmaxf(mm, m2);
            ss = ss * EXP2(mm - mn) + s2 * EXP2(m2 - mn);
            vsS[tid] = LM2 - (mn + LOG2(ss));         // v in log2 domain
        }
        __syncthreads();                              // E: vsS ready
    }

    // ===== PI phase (log2 dom): p = 2^(u2+v2-c2); cost = sum p*c2 / KSC =====
    float csum = 0.0f;
    {
        float4 v0 = *(const float4*)(vsS + 4 * l);
        float4 v1 = *(const float4*)(vsS + 256 + 4 * l);
#pragma unroll
        for (int rr = 0; rr < 2; ++rr) {
            int i = bt * 32 + w * 2 + rr;
            float uu = uPrev[rr];
            float* prow = pi + ((size_t)(b * NN + i)) * NN;
            float4 c0 = cR2[rr][0], c1 = cR2[rr][1];
            float4 p0, p1;
            p0.x = EXP2(uu + v0.x - c0.x);
            p0.y = EXP2(uu + v0.y - c0.y);
            p0.z = EXP2(uu + v0.z - c0.z);
            p0.w = EXP2(uu + v0.w - c0.w);
            p1.x = EXP2(uu + v1.x - c1.x);
            p1.y = EXP2(uu + v1.y - c1.y);
            p1.z = EXP2(uu + v1.z - c1.z);
            p1.w = EXP2(uu + v1.w - c1.w);
            *(float4*)(prow + 4 * l) = p0;
            *(float4*)(prow + 256 + 4 * l) = p1;
            csum += p0.x * c0.x + p0.y * c0.y + p0.z * c0.z + p0.w * c0.w +
                    p1.x * c1.x + p1.y * c1.y + p1.z * c1.z + p1.w * c1.w;
        }
    }
#pragma unroll
    for (int off = 32; off; off >>= 1) csum += __shfl_xor(csum, off, 64);
    if (l == 0) partS[w] = csum;
    __syncthreads();
    if (tid == 0) {
        float s = 0.0f;
#pragma unroll
        for (int q = 0; q < 16; ++q) s += partS[q];
        ST_REL(costPart + b * 16 + bt, s * INVK);     // back to raw-C domain
    }
    barrier_full(false);                              // cost partials visible
    if (bt == 0 && tid == 0) {
        float s = 0.0f;
        for (int q = 0; q < 16; ++q) s += LD_REL(costPart + b * 16 + q);
        cost[b] = s;                                  // plain store; kernel-end release
    }
}

extern "C" void kernel_launch(void* const* d_in, const int* in_sizes, int n_in,
                              void* d_out, int out_size, void* d_ws, size_t ws_size,
                              hipStream_t stream) {
    const float* x = (const float*)d_in[0];
    const float* y = (const float*)d_in[1];

    // Output layout: cost[16], pi[16*512*512], C[16*512*512]
    float* cost = (float*)d_out;
    float* pi   = cost + 16;
    float* C    = pi + (size_t)NB * NN * NN;

    float* f = (float*)d_ws;
    float* errPart  = f + WS_ERRPART;
    float* errB     = f + WS_ERRB;
    float* costPart = f + WS_COSTPART;
    int*   frozenPub = (int*)(f + WS_FPUB);
    unsigned* flags  = (unsigned*)(f + WS_FLAGS);
    unsigned* barCnt = (unsigned*)(f + WS_BARCNT);
    unsigned long long* msPart = (unsigned long long*)(f + WS_MSPART);

    hipLaunchKernelGGL(k_zero, dim3((WS_TOTAL + 255) / 256), dim3(256), 0, stream, f);

    void* args[] = {(void*)&x, (void*)&y, (void*)&C, (void*)&pi, (void*)&cost,
                    (void*)&errPart, (void*)&errB, (void*)&costPart,
                    (void*)&frozenPub, (void*)&flags, (void*)&barCnt, (void*)&msPart};
    hipError_t e = hipLaunchCooperativeKernel((const void*)k_sink, dim3(256), dim3(1024),
                                              args, 0, stream);
    if (e != hipSuccess) {
        // Fallback: plain launch. 256 blocks x 1024 thr, 1 block/CU -> co-resident.
        hipLaunchKernelGGL(k_sink, dim3(256), dim3(1024), 0, stream,
                           x, y, C, pi, cost, errPart, errB, costPart,
                           frozenPub, flags, barCnt, msPart);
    }
}